// Round 2
// baseline (220.936 us; speedup 1.0000x reference)
//
#include <hip/hip_runtime.h>
#include <hip/hip_bf16.h>
#include <cstdint>
#include <cstddef>

typedef __attribute__((ext_vector_type(8))) short bf16x8;
typedef __attribute__((ext_vector_type(4))) float f32x4;

#define GLD_LDS16(gptr, lptr)                                                  \
  __builtin_amdgcn_global_load_lds(                                            \
      (const __attribute__((address_space(1))) void*)(gptr),                   \
      (__attribute__((address_space(3))) void*)(lptr), 16, 0, 0)

// ---------------- RMSNorm: x[4096][1024] f32 -> h bf16 ----------------
__global__ __launch_bounds__(256) void rmsnorm_kernel(
    const float* __restrict__ x, const float* __restrict__ w,
    __hip_bfloat16* __restrict__ h) {
  const int row = blockIdx.x;
  const int tid = threadIdx.x;
  const float4 v = reinterpret_cast<const float4*>(x + (size_t)row * 1024)[tid];
  float ss = v.x * v.x + v.y * v.y + v.z * v.z + v.w * v.w;
#pragma unroll
  for (int off = 32; off >= 1; off >>= 1) ss += __shfl_down(ss, off);
  __shared__ float red[4];
  if ((tid & 63) == 0) red[tid >> 6] = ss;
  __syncthreads();
  const float inv =
      rsqrtf((red[0] + red[1] + red[2] + red[3]) * (1.0f / 1024.0f) + 1e-6f);
  const float4 wv = reinterpret_cast<const float4*>(w)[tid];
  __hip_bfloat16* hp = h + (size_t)row * 1024 + tid * 4;
  hp[0] = __float2bfloat16(v.x * inv * wv.x);
  hp[1] = __float2bfloat16(v.y * inv * wv.y);
  hp[2] = __float2bfloat16(v.z * inv * wv.z);
  hp[3] = __float2bfloat16(v.w * inv * wv.w);
}

// ------- transpose+cast: src[R][C] f32 -> dst[C][R] bf16 --------
__global__ __launch_bounds__(256) void transpose_cast_kernel(
    const float* __restrict__ src, __hip_bfloat16* __restrict__ dst,
    int R, int C) {
  __shared__ float tile[32][33];
  const int bx = blockIdx.x * 32;  // C dim
  const int by = blockIdx.y * 32;  // R dim
  const int tx = threadIdx.x;      // 0..31
  const int ty = threadIdx.y;      // 0..7
#pragma unroll
  for (int j = 0; j < 32; j += 8)
    tile[ty + j][tx] = src[(size_t)(by + ty + j) * C + bx + tx];
  __syncthreads();
#pragma unroll
  for (int j = 0; j < 32; j += 8)
    dst[(size_t)(bx + ty + j) * R + by + tx] = __float2bfloat16(tile[tx][ty + j]);
}

// ---------------- GEMM: C[M][N] = A[M][K] * BT[N][K]^T ----------------
// 128x128 tile, BK=32, 256 threads (4 waves, 2x2), mfma 16x16x32 bf16.
template <int RESID>
__global__ __launch_bounds__(256) void gemm_bt_kernel(
    const __hip_bfloat16* __restrict__ A, const __hip_bfloat16* __restrict__ BT,
    void* __restrict__ Cout, const float* __restrict__ resid,
    int M, int N, int K) {
  __shared__ __align__(16) __hip_bfloat16 As[128 * 32];
  __shared__ __align__(16) __hip_bfloat16 Bs[128 * 32];
  const int tid = threadIdx.x;
  const int lane = tid & 63;
  const int wid = tid >> 6;
  const int m0 = blockIdx.y * 128;
  const int n0 = blockIdx.x * 128;
  const int wr = wid >> 1, wc = wid & 1;  // wave tile 64x64
  f32x4 acc[4][4] = {};
  const int nk = K >> 5;
  const int lr = lane & 15, lk = lane >> 4;
  for (int kt = 0; kt < nk; ++kt) {
#pragma unroll
    for (int it = 0; it < 2; ++it) {
      const int c = wid * 2 + it;        // chunk 0..7 (1KB each)
      const int e = c * 512 + lane * 8;  // elem idx (only for global addr)
      const int row = e >> 5, col = e & 31;
      GLD_LDS16(A + (size_t)(m0 + row) * K + kt * 32 + col, As + c * 512);
      GLD_LDS16(BT + (size_t)(n0 + row) * K + kt * 32 + col, Bs + c * 512);
    }
    __syncthreads();
    bf16x8 af[4], bfr[4];
#pragma unroll
    for (int i = 0; i < 4; ++i)
      af[i] = *(const bf16x8*)(As + (wr * 64 + i * 16 + lr) * 32 + lk * 8);
#pragma unroll
    for (int j = 0; j < 4; ++j)
      bfr[j] = *(const bf16x8*)(Bs + (wc * 64 + j * 16 + lr) * 32 + lk * 8);
#pragma unroll
    for (int i = 0; i < 4; ++i)
#pragma unroll
      for (int j = 0; j < 4; ++j)
        acc[i][j] = __builtin_amdgcn_mfma_f32_16x16x32_bf16(af[i], bfr[j],
                                                            acc[i][j], 0, 0, 0);
    __syncthreads();
  }
// epilogue: C/D layout col=lane&15, row=(lane>>4)*4+reg (m89-verified)
#pragma unroll
  for (int i = 0; i < 4; ++i)
#pragma unroll
    for (int j = 0; j < 4; ++j)
#pragma unroll
      for (int r = 0; r < 4; ++r) {
        const int row = m0 + wr * 64 + i * 16 + lk * 4 + r;
        const int col = n0 + wc * 64 + j * 16 + lr;
        const float v = acc[i][j][r];
        if (RESID) {
          ((float*)Cout)[(size_t)row * N + col] =
              resid[(size_t)row * N + col] + v;
        } else {
          ((__hip_bfloat16*)Cout)[(size_t)row * N + col] = __float2bfloat16(v);
        }
      }
}

// ---------------- Flash attention ----------------
// grid (32 qtiles, 32 b*h). block 256 = 4 waves x 16 q-rows. KV tile 64.
// qkv layout: [4096][3072] bf16, q at col h*64, k at 1024+h*64, v at 2048+h*64.
// ctx layout: [4096][1024] bf16, col = h*64+hd.
__global__ __launch_bounds__(256) void attn_kernel(
    const __hip_bfloat16* __restrict__ qkv, __hip_bfloat16* __restrict__ ctx) {
  const int qt = blockIdx.x, bh = blockIdx.y;
  const int b = bh >> 4, h = bh & 15;
  const int tid = threadIdx.x, lane = tid & 63, wid = tid >> 6;
  const size_t tok0 = (size_t)b * 2048;
  const int q0 = qt * 64 + wid * 16;  // wave's q rows within sequence
  const int lr = lane & 15, lk = lane >> 4;

  __shared__ __align__(16) __hip_bfloat16 Kl[64 * 72];
  __shared__ __align__(16) __hip_bfloat16 Vt[64 * 72];  // [hd][kv] padded
  __shared__ __align__(16) __hip_bfloat16 Pl[4 * 16 * 72];
  __hip_bfloat16* pw = Pl + wid * (16 * 72);

  // Q fragments held in registers whole kernel
  bf16x8 qf[2];
  {
    const __hip_bfloat16* qptr = qkv + (tok0 + q0 + lr) * 3072 + h * 64;
    qf[0] = *(const bf16x8*)(qptr + lk * 8);
    qf[1] = *(const bf16x8*)(qptr + 32 + lk * 8);
  }

  f32x4 oacc[4] = {};
  float mrow[4] = {-1e30f, -1e30f, -1e30f, -1e30f};
  float lrow[4] = {0.f, 0.f, 0.f, 0.f};
  const float scale = 0.125f;  // 1/sqrt(64)

  for (int kvt = 0; kvt < 32; ++kvt) {
    __syncthreads();  // previous tile's reads done before overwrite
    {
      // 64 rows x 64 cols; 256 threads x 16 elems. r=row, c0=col base.
      const int r = tid >> 2, c0 = (tid & 3) * 16;
      const __hip_bfloat16* base =
          qkv + (tok0 + kvt * 64 + r) * 3072 + h * 64;
      const bf16x8 k0 = *(const bf16x8*)(base + 1024 + c0);
      const bf16x8 k1 = *(const bf16x8*)(base + 1024 + c0 + 8);
      *(bf16x8*)(Kl + r * 72 + c0) = k0;
      *(bf16x8*)(Kl + r * 72 + c0 + 8) = k1;
      const bf16x8 v0 = *(const bf16x8*)(base + 2048 + c0);
      const bf16x8 v1 = *(const bf16x8*)(base + 2048 + c0 + 8);
      const __hip_bfloat16* v0e = (const __hip_bfloat16*)&v0;
      const __hip_bfloat16* v1e = (const __hip_bfloat16*)&v1;
#pragma unroll
      for (int j = 0; j < 8; ++j) Vt[(c0 + j) * 72 + r] = v0e[j];
#pragma unroll
      for (int j = 0; j < 8; ++j) Vt[(c0 + 8 + j) * 72 + r] = v1e[j];
    }
    __syncthreads();

    // S = Q * K^T  (4 col-frags x 2 k-chunks)
    f32x4 sacc[4] = {};
#pragma unroll
    for (int nf = 0; nf < 4; ++nf)
#pragma unroll
      for (int kc = 0; kc < 2; ++kc) {
        const bf16x8 kf =
            *(const bf16x8*)(Kl + (nf * 16 + lr) * 72 + kc * 32 + lk * 8);
        sacc[nf] =
            __builtin_amdgcn_mfma_f32_16x16x32_bf16(qf[kc], kf, sacc[nf], 0, 0, 0);
      }
#pragma unroll
    for (int nf = 0; nf < 4; ++nf)
#pragma unroll
      for (int r = 0; r < 4; ++r) sacc[nf][r] *= scale;

    // online softmax per q-row (row = lk*4+r, cols spread over 16 lanes+frags)
    float alpha[4];
#pragma unroll
    for (int r = 0; r < 4; ++r) {
      float mx = fmaxf(fmaxf(sacc[0][r], sacc[1][r]),
                       fmaxf(sacc[2][r], sacc[3][r]));
#pragma unroll
      for (int off = 8; off >= 1; off >>= 1) mx = fmaxf(mx, __shfl_xor(mx, off));
      const float mn = fmaxf(mrow[r], mx);
      alpha[r] = __expf(mrow[r] - mn);
      mrow[r] = mn;
      float ps = 0.f;
#pragma unroll
      for (int nf = 0; nf < 4; ++nf) {
        const float p = __expf(sacc[nf][r] - mn);
        sacc[nf][r] = p;
        ps += p;
      }
#pragma unroll
      for (int off = 8; off >= 1; off >>= 1) ps += __shfl_xor(ps, off);
      lrow[r] = alpha[r] * lrow[r] + ps;
    }

    // P -> LDS (S-layout rows lk*4+r, col lr per frag)
#pragma unroll
    for (int nf = 0; nf < 4; ++nf)
#pragma unroll
      for (int r = 0; r < 4; ++r)
        pw[(lk * 4 + r) * 72 + nf * 16 + lr] = __float2bfloat16(sacc[nf][r]);

    // rescale O
#pragma unroll
    for (int j = 0; j < 4; ++j)
#pragma unroll
      for (int r = 0; r < 4; ++r) oacc[j][r] *= alpha[r];

    __syncthreads();  // P visible (also keeps waves in lockstep)

    // O += P * V   (A = P rows lr, B = Vt rows j*16+lr)
#pragma unroll
    for (int j = 0; j < 4; ++j)
#pragma unroll
      for (int kc = 0; kc < 2; ++kc) {
        const bf16x8 pf = *(const bf16x8*)(pw + lr * 72 + kc * 32 + lk * 8);
        const bf16x8 vf =
            *(const bf16x8*)(Vt + (j * 16 + lr) * 72 + kc * 32 + lk * 8);
        oacc[j] = __builtin_amdgcn_mfma_f32_16x16x32_bf16(pf, vf, oacc[j], 0, 0, 0);
      }
  }

  // epilogue: normalize and store ctx
#pragma unroll
  for (int j = 0; j < 4; ++j)
#pragma unroll
    for (int r = 0; r < 4; ++r) {
      const int row = q0 + lk * 4 + r;
      const float v = oacc[j][r] / lrow[r];
      ctx[(tok0 + row) * 1024 + h * 64 + j * 16 + lr] = __float2bfloat16(v);
    }
}

extern "C" void kernel_launch(void* const* d_in, const int* in_sizes, int n_in,
                              void* d_out, int out_size, void* d_ws,
                              size_t ws_size, hipStream_t stream) {
  const float* x = (const float*)d_in[0];       // [2,2048,1024]
  const float* norm_w = (const float*)d_in[1];  // [1024]
  const float* w_qkv = (const float*)d_in[2];   // [1024,3072]
  const float* w_proj = (const float*)d_in[3];  // [1024,1024]
  float* out = (float*)d_out;                   // [2,2048,1024] f32

  char* ws = (char*)d_ws;
  __hip_bfloat16* h = (__hip_bfloat16*)(ws);                              // 8 MB
  __hip_bfloat16* wqkvT = (__hip_bfloat16*)(ws + (size_t)8 * 1024 * 1024);   // 6 MB
  __hip_bfloat16* wprojT = (__hip_bfloat16*)(ws + (size_t)14 * 1024 * 1024); // 2 MB
  __hip_bfloat16* qkv = (__hip_bfloat16*)(ws + (size_t)16 * 1024 * 1024);    // 24 MB
  __hip_bfloat16* ctx = (__hip_bfloat16*)(ws + (size_t)40 * 1024 * 1024);    // 8 MB

  rmsnorm_kernel<<<dim3(4096), dim3(256), 0, stream>>>(x, norm_w, h);
  transpose_cast_kernel<<<dim3(96, 32), dim3(32, 8), 0, stream>>>(w_qkv, wqkvT,
                                                                  1024, 3072);
  transpose_cast_kernel<<<dim3(32, 32), dim3(32, 8), 0, stream>>>(
      w_proj, wprojT, 1024, 1024);
  gemm_bt_kernel<0><<<dim3(24, 32), dim3(256), 0, stream>>>(
      h, wqkvT, (void*)qkv, nullptr, 4096, 3072, 1024);
  attn_kernel<<<dim3(32, 32), dim3(256), 0, stream>>>(qkv, ctx);
  gemm_bt_kernel<1><<<dim3(8, 32), dim3(256), 0, stream>>>(
      ctx, wprojT, (void*)out, x, 4096, 1024, 1024);
}

// Round 3
// 189.746 us; speedup vs baseline: 1.1644x; 1.1644x over previous
//
#include <hip/hip_runtime.h>
#include <hip/hip_bf16.h>
#include <cstdint>
#include <cstddef>

typedef __attribute__((ext_vector_type(8))) short bf16x8;
typedef __attribute__((ext_vector_type(4))) float f32x4;

#define GLD_LDS16(gptr, lptr)                                                  \
  __builtin_amdgcn_global_load_lds(                                            \
      (const __attribute__((address_space(1))) void*)(gptr),                   \
      (__attribute__((address_space(3))) void*)(lptr), 16, 0, 0)

// ---------------- RMSNorm: x[4096][1024] f32 -> h bf16 ----------------
__global__ __launch_bounds__(256) void rmsnorm_kernel(
    const float* __restrict__ x, const float* __restrict__ w,
    __hip_bfloat16* __restrict__ h) {
  const int row = blockIdx.x;
  const int tid = threadIdx.x;
  const float4 v = reinterpret_cast<const float4*>(x + (size_t)row * 1024)[tid];
  float ss = v.x * v.x + v.y * v.y + v.z * v.z + v.w * v.w;
#pragma unroll
  for (int off = 32; off >= 1; off >>= 1) ss += __shfl_down(ss, off);
  __shared__ float red[4];
  if ((tid & 63) == 0) red[tid >> 6] = ss;
  __syncthreads();
  const float inv =
      rsqrtf((red[0] + red[1] + red[2] + red[3]) * (1.0f / 1024.0f) + 1e-6f);
  const float4 wv = reinterpret_cast<const float4*>(w)[tid];
  __hip_bfloat16* hp = h + (size_t)row * 1024 + tid * 4;
  hp[0] = __float2bfloat16(v.x * inv * wv.x);
  hp[1] = __float2bfloat16(v.y * inv * wv.y);
  hp[2] = __float2bfloat16(v.z * inv * wv.z);
  hp[3] = __float2bfloat16(v.w * inv * wv.w);
}

// ------- transpose+cast: src[R][C] f32 -> dst[C][R] bf16 --------
__global__ __launch_bounds__(256) void transpose_cast_kernel(
    const float* __restrict__ src, __hip_bfloat16* __restrict__ dst,
    int R, int C) {
  __shared__ float tile[32][33];
  const int bx = blockIdx.x * 32;  // C dim
  const int by = blockIdx.y * 32;  // R dim
  const int tx = threadIdx.x;      // 0..31
  const int ty = threadIdx.y;      // 0..7
#pragma unroll
  for (int j = 0; j < 32; j += 8)
    tile[ty + j][tx] = src[(size_t)(by + ty + j) * C + bx + tx];
  __syncthreads();
#pragma unroll
  for (int j = 0; j < 32; j += 8)
    dst[(size_t)(bx + ty + j) * R + by + tx] = __float2bfloat16(tile[tx][ty + j]);
}

// ---------------- GEMM: C[M][N] = A[M][K] * BT[N][K]^T ----------------
// 128x128 tile, BK=32, 256 threads (4 waves, 2x2), mfma 16x16x32 bf16.
template <int RESID>
__global__ __launch_bounds__(256) void gemm_bt_kernel(
    const __hip_bfloat16* __restrict__ A, const __hip_bfloat16* __restrict__ BT,
    void* __restrict__ Cout, const float* __restrict__ resid,
    int M, int N, int K) {
  __shared__ __align__(16) __hip_bfloat16 As[128 * 32];
  __shared__ __align__(16) __hip_bfloat16 Bs[128 * 32];
  const int tid = threadIdx.x;
  const int lane = tid & 63;
  const int wid = tid >> 6;
  const int m0 = blockIdx.y * 128;
  const int n0 = blockIdx.x * 128;
  const int wr = wid >> 1, wc = wid & 1;  // wave tile 64x64
  f32x4 acc[4][4] = {};
  const int nk = K >> 5;
  const int lr = lane & 15, lk = lane >> 4;
  for (int kt = 0; kt < nk; ++kt) {
#pragma unroll
    for (int it = 0; it < 2; ++it) {
      const int c = wid * 2 + it;        // chunk 0..7 (1KB each)
      const int e = c * 512 + lane * 8;  // elem idx (only for global addr)
      const int row = e >> 5, col = e & 31;
      GLD_LDS16(A + (size_t)(m0 + row) * K + kt * 32 + col, As + c * 512);
      GLD_LDS16(BT + (size_t)(n0 + row) * K + kt * 32 + col, Bs + c * 512);
    }
    __syncthreads();
    bf16x8 af[4], bfr[4];
#pragma unroll
    for (int i = 0; i < 4; ++i)
      af[i] = *(const bf16x8*)(As + (wr * 64 + i * 16 + lr) * 32 + lk * 8);
#pragma unroll
    for (int j = 0; j < 4; ++j)
      bfr[j] = *(const bf16x8*)(Bs + (wc * 64 + j * 16 + lr) * 32 + lk * 8);
#pragma unroll
    for (int i = 0; i < 4; ++i)
#pragma unroll
      for (int j = 0; j < 4; ++j)
        acc[i][j] = __builtin_amdgcn_mfma_f32_16x16x32_bf16(af[i], bfr[j],
                                                            acc[i][j], 0, 0, 0);
    __syncthreads();
  }
// epilogue: C/D layout col=lane&15, row=(lane>>4)*4+reg (m89-verified)
#pragma unroll
  for (int i = 0; i < 4; ++i)
#pragma unroll
    for (int j = 0; j < 4; ++j)
#pragma unroll
      for (int r = 0; r < 4; ++r) {
        const int row = m0 + wr * 64 + i * 16 + lk * 4 + r;
        const int col = n0 + wc * 64 + j * 16 + lr;
        const float v = acc[i][j][r];
        if (RESID) {
          ((float*)Cout)[(size_t)row * N + col] =
              resid[(size_t)row * N + col] + v;
        } else {
          ((__hip_bfloat16*)Cout)[(size_t)row * N + col] = __float2bfloat16(v);
        }
      }
}

// ---------------- Flash attention (swapped QK^T, in-register softmax) -------
// grid (32 qtiles, 32 b*h). block 256 = 4 waves x 16 q-rows. KV tile 64.
// qk  layout: [4096][2048] bf16 (Q cols 0..1023, K cols 1024..2047)
// vT  layout: [1024][4096] bf16 (V^T: row = h*64+d, col = token)
// ctx layout: [4096][1024] bf16.
__global__ __launch_bounds__(256, 4) void attn_kernel(
    const __hip_bfloat16* __restrict__ qk, const __hip_bfloat16* __restrict__ vT,
    __hip_bfloat16* __restrict__ ctx) {
  const int qt = blockIdx.x, bh = blockIdx.y;
  const int b = bh >> 4, h = bh & 15;
  const int tid = threadIdx.x, lane = tid & 63, wid = tid >> 6;
  const size_t tok0 = (size_t)b * 2048;
  const int q0 = qt * 64 + wid * 16;
  const int lr = lane & 15, lk = lane >> 4;

  __shared__ __align__(16) __hip_bfloat16 Kl[2][64 * 72];
  __shared__ __align__(16) __hip_bfloat16 Vt[2][64 * 72];

  // staging geometry: 256 threads cover 64 rows x 64 cols, 16 elems each
  const int sr = tid >> 2;        // K: token row | V^T: d row
  const int sc = (tid & 3) * 16;  // column base
  const __hip_bfloat16* kbase = qk + tok0 * 2048 + 1024 + h * 64;
  const __hip_bfloat16* vbase = vT + (size_t)(h * 64 + sr) * 4096 + tok0;

  // Q fragments (B-operand of swapped QK^T), pre-scaled by 1/sqrt(64)*log2(e)
  bf16x8 qf[2];
  {
    const __hip_bfloat16* qptr = qk + (tok0 + q0 + lr) * 2048 + h * 64;
    bf16x8 qa = *(const bf16x8*)(qptr + lk * 8);
    bf16x8 qb = *(const bf16x8*)(qptr + 32 + lk * 8);
    const float c = 0.125f * 1.44269504f;
    const __hip_bfloat16* ia = (const __hip_bfloat16*)&qa;
    const __hip_bfloat16* ib = (const __hip_bfloat16*)&qb;
    __hip_bfloat16* oa = (__hip_bfloat16*)&qf[0];
    __hip_bfloat16* ob = (__hip_bfloat16*)&qf[1];
#pragma unroll
    for (int i = 0; i < 8; ++i) {
      oa[i] = __float2bfloat16(__bfloat162float(ia[i]) * c);
      ob[i] = __float2bfloat16(__bfloat162float(ib[i]) * c);
    }
  }

  bf16x8 kreg0, kreg1, vreg0, vreg1;
  auto load_tile = [&](int t) {
    const __hip_bfloat16* kp = kbase + (size_t)(t * 64 + sr) * 2048 + sc;
    kreg0 = *(const bf16x8*)kp;
    kreg1 = *(const bf16x8*)(kp + 8);
    const __hip_bfloat16* vp = vbase + t * 64 + sc;
    vreg0 = *(const bf16x8*)vp;
    vreg1 = *(const bf16x8*)(vp + 8);
  };
  auto write_tile = [&](int bf) {
    *(bf16x8*)(Kl[bf] + sr * 72 + sc) = kreg0;
    *(bf16x8*)(Kl[bf] + sr * 72 + sc + 8) = kreg1;
    *(bf16x8*)(Vt[bf] + sr * 72 + sc) = vreg0;
    *(bf16x8*)(Vt[bf] + sr * 72 + sc + 8) = vreg1;
  };

  f32x4 oacc[4] = {};
  float mrow = -3e38f, lrow = 0.f;

  const int s0 = lr + ((2 * lk) & 3) * 16;
  const int s1 = lr + ((2 * lk + 1) & 3) * 16;
  const bool hi = (lk >= 2);

  load_tile(0);
  write_tile(0);
  __syncthreads();

  for (int kvt = 0; kvt < 32; ++kvt) {
    const int cur = kvt & 1;
    if (kvt + 1 < 32) load_tile(kvt + 1);

    // S^T = K * Q^T : st[nf][r] = S[q=lr][tok=nf*16+lk*4+r] (exp2 domain)
    f32x4 st[4] = {};
#pragma unroll
    for (int nf = 0; nf < 4; ++nf)
#pragma unroll
      for (int kc = 0; kc < 2; ++kc) {
        const bf16x8 kf =
            *(const bf16x8*)(Kl[cur] + (nf * 16 + lr) * 72 + kc * 32 + lk * 8);
        st[nf] =
            __builtin_amdgcn_mfma_f32_16x16x32_bf16(kf, qf[kc], st[nf], 0, 0, 0);
      }

    // online softmax, fully per-lane for q = lr
    float mx = fmaxf(fmaxf(st[0][0], st[0][1]), fmaxf(st[0][2], st[0][3]));
#pragma unroll
    for (int nf = 1; nf < 4; ++nf)
      mx = fmaxf(mx, fmaxf(fmaxf(st[nf][0], st[nf][1]),
                           fmaxf(st[nf][2], st[nf][3])));
    mx = fmaxf(mx, __shfl_xor(mx, 16));
    mx = fmaxf(mx, __shfl_xor(mx, 32));
    const float mn = fmaxf(mrow, mx);
    const float alpha = exp2f(mrow - mn);
    mrow = mn;

    float ps = 0.f;
    uint32_t pku[4][2];
#pragma unroll
    for (int nf = 0; nf < 4; ++nf) {
      float p0 = exp2f(st[nf][0] - mn), p1 = exp2f(st[nf][1] - mn);
      float p2 = exp2f(st[nf][2] - mn), p3 = exp2f(st[nf][3] - mn);
      ps += (p0 + p1) + (p2 + p3);
      __hip_bfloat16 h0 = __float2bfloat16(p0), h1 = __float2bfloat16(p1);
      __hip_bfloat16 h2 = __float2bfloat16(p2), h3 = __float2bfloat16(p3);
      pku[nf][0] = (uint32_t)*(uint16_t*)&h0 | ((uint32_t)*(uint16_t*)&h1 << 16);
      pku[nf][1] = (uint32_t)*(uint16_t*)&h2 | ((uint32_t)*(uint16_t*)&h3 << 16);
    }
    ps += __shfl_xor(ps, 16);
    ps += __shfl_xor(ps, 32);
    lrow = alpha * lrow + ps;

    // redistribute P into PV A-fragments: tok kc*32+lk*8+j from lane
    // lr+((2lk+(j>>2))&3)*16, reg nf'=kc*2+(lk>>1), r'=j&3
    bf16x8 pfrag[2];
#pragma unroll
    for (int kc = 0; kc < 2; ++kc) {
      const int nA = kc * 2, nB = kc * 2 + 1;
      uint32_t a0A = __shfl((int)pku[nA][0], s0), a0B = __shfl((int)pku[nB][0], s0);
      uint32_t a1A = __shfl((int)pku[nA][1], s0), a1B = __shfl((int)pku[nB][1], s0);
      uint32_t a2A = __shfl((int)pku[nA][0], s1), a2B = __shfl((int)pku[nB][0], s1);
      uint32_t a3A = __shfl((int)pku[nA][1], s1), a3B = __shfl((int)pku[nB][1], s1);
      uint32_t u[4] = {hi ? a0B : a0A, hi ? a1B : a1A, hi ? a2B : a2A,
                       hi ? a3B : a3A};
      pfrag[kc] = *(bf16x8*)u;
    }

    // rescale O (O rows are q = lk*4+r -> fetch alpha from lane lk*4+r)
#pragma unroll
    for (int r = 0; r < 4; ++r) {
      const float ar = __shfl(alpha, lk * 4 + r);
      oacc[0][r] *= ar;
      oacc[1][r] *= ar;
      oacc[2][r] *= ar;
      oacc[3][r] *= ar;
    }

    // O += P * V
#pragma unroll
    for (int j = 0; j < 4; ++j)
#pragma unroll
      for (int kc = 0; kc < 2; ++kc) {
        const bf16x8 vf =
            *(const bf16x8*)(Vt[cur] + (j * 16 + lr) * 72 + kc * 32 + lk * 8);
        oacc[j] =
            __builtin_amdgcn_mfma_f32_16x16x32_bf16(pfrag[kc], vf, oacc[j], 0, 0, 0);
      }

    if (kvt + 1 < 32) write_tile(cur ^ 1);
    __syncthreads();
  }

  // epilogue
#pragma unroll
  for (int r = 0; r < 4; ++r) {
    const float li = 1.0f / __shfl(lrow, lk * 4 + r);
    const int row = q0 + lk * 4 + r;
#pragma unroll
    for (int j = 0; j < 4; ++j)
      ctx[(tok0 + row) * 1024 + h * 64 + j * 16 + lr] =
          __float2bfloat16(oacc[j][r] * li);
  }
}

extern "C" void kernel_launch(void* const* d_in, const int* in_sizes, int n_in,
                              void* d_out, int out_size, void* d_ws,
                              size_t ws_size, hipStream_t stream) {
  const float* x = (const float*)d_in[0];       // [2,2048,1024]
  const float* norm_w = (const float*)d_in[1];  // [1024]
  const float* w_qkv = (const float*)d_in[2];   // [1024,3072]
  const float* w_proj = (const float*)d_in[3];  // [1024,1024]
  float* out = (float*)d_out;                   // [2,2048,1024] f32

  char* ws = (char*)d_ws;
  __hip_bfloat16* hbuf = (__hip_bfloat16*)(ws);                               // 8 MB
  __hip_bfloat16* wqkvT = (__hip_bfloat16*)(ws + (size_t)8 * 1024 * 1024);    // 6 MB
  __hip_bfloat16* wprojT = (__hip_bfloat16*)(ws + (size_t)14 * 1024 * 1024);  // 2 MB
  __hip_bfloat16* qkbuf = (__hip_bfloat16*)(ws + (size_t)16 * 1024 * 1024);   // 16 MB
  __hip_bfloat16* vTbuf = (__hip_bfloat16*)(ws + (size_t)32 * 1024 * 1024);   // 8 MB
  __hip_bfloat16* ctx = (__hip_bfloat16*)(ws + (size_t)40 * 1024 * 1024);     // 8 MB

  rmsnorm_kernel<<<dim3(4096), dim3(256), 0, stream>>>(x, norm_w, hbuf);
  transpose_cast_kernel<<<dim3(96, 32), dim3(32, 8), 0, stream>>>(w_qkv, wqkvT,
                                                                  1024, 3072);
  transpose_cast_kernel<<<dim3(32, 32), dim3(32, 8), 0, stream>>>(
      w_proj, wprojT, 1024, 1024);
  // QK GEMM: [4096][2048] = h * (wqkvT rows 0..2047)^T
  gemm_bt_kernel<0><<<dim3(16, 32), dim3(256), 0, stream>>>(
      hbuf, wqkvT, (void*)qkbuf, nullptr, 4096, 2048, 1024);
  // V^T GEMM: [1024][4096] = (wqkvT rows 2048..3071) * h^T
  gemm_bt_kernel<0><<<dim3(32, 8), dim3(256), 0, stream>>>(
      wqkvT + (size_t)2048 * 1024, hbuf, (void*)vTbuf, nullptr, 1024, 4096,
      1024);
  attn_kernel<<<dim3(32, 32), dim3(256), 0, stream>>>(qkbuf, vTbuf, ctx);
  gemm_bt_kernel<1><<<dim3(8, 32), dim3(256), 0, stream>>>(
      ctx, wprojT, (void*)out, x, 4096, 1024, 1024);
}

// Round 4
// 167.322 us; speedup vs baseline: 1.3204x; 1.1340x over previous
//
#include <hip/hip_runtime.h>
#include <hip/hip_bf16.h>
#include <cstdint>
#include <cstddef>

typedef __attribute__((ext_vector_type(8))) short bf16x8;
typedef __attribute__((ext_vector_type(4))) float f32x4;
typedef __attribute__((ext_vector_type(16))) float f32x16;

#define GLD_LDS16(gptr, lptr)                                                  \
  __builtin_amdgcn_global_load_lds(                                            \
      (const __attribute__((address_space(1))) void*)(gptr),                   \
      (__attribute__((address_space(3))) void*)(lptr), 16, 0, 0)

__device__ __forceinline__ uint32_t bfpack(float a, float b) {
  __hip_bfloat16 ha = __float2bfloat16(a), hb = __float2bfloat16(b);
  return (uint32_t)*(uint16_t*)&ha | ((uint32_t)*(uint16_t*)&hb << 16);
}

// ---------------- RMSNorm: x[4096][1024] f32 -> h bf16 ----------------
__global__ __launch_bounds__(256) void rmsnorm_kernel(
    const float* __restrict__ x, const float* __restrict__ w,
    __hip_bfloat16* __restrict__ h) {
  const int row = blockIdx.x;
  const int tid = threadIdx.x;
  const float4 v = reinterpret_cast<const float4*>(x + (size_t)row * 1024)[tid];
  float ss = v.x * v.x + v.y * v.y + v.z * v.z + v.w * v.w;
#pragma unroll
  for (int off = 32; off >= 1; off >>= 1) ss += __shfl_down(ss, off);
  __shared__ float red[4];
  if ((tid & 63) == 0) red[tid >> 6] = ss;
  __syncthreads();
  const float inv =
      rsqrtf((red[0] + red[1] + red[2] + red[3]) * (1.0f / 1024.0f) + 1e-6f);
  const float4 wv = reinterpret_cast<const float4*>(w)[tid];
  __hip_bfloat16* hp = h + (size_t)row * 1024 + tid * 4;
  hp[0] = __float2bfloat16(v.x * inv * wv.x);
  hp[1] = __float2bfloat16(v.y * inv * wv.y);
  hp[2] = __float2bfloat16(v.z * inv * wv.z);
  hp[3] = __float2bfloat16(v.w * inv * wv.w);
}

// ------- transpose+cast: src[R][C] f32 -> dst[C][R] bf16 --------
__global__ __launch_bounds__(256) void transpose_cast_kernel(
    const float* __restrict__ src, __hip_bfloat16* __restrict__ dst,
    int R, int C) {
  __shared__ float tile[32][33];
  const int bx = blockIdx.x * 32;  // C dim
  const int by = blockIdx.y * 32;  // R dim
  const int tx = threadIdx.x;      // 0..31
  const int ty = threadIdx.y;      // 0..7
#pragma unroll
  for (int j = 0; j < 32; j += 8)
    tile[ty + j][tx] = src[(size_t)(by + ty + j) * C + bx + tx];
  __syncthreads();
#pragma unroll
  for (int j = 0; j < 32; j += 8)
    dst[(size_t)(bx + ty + j) * R + by + tx] = __float2bfloat16(tile[tx][ty + j]);
}

// ---------------- GEMM: C[M][N] = A[M][K] * BT[N][K]^T ----------------
template <int RESID>
__global__ __launch_bounds__(256) void gemm_bt_kernel(
    const __hip_bfloat16* __restrict__ A, const __hip_bfloat16* __restrict__ BT,
    void* __restrict__ Cout, const float* __restrict__ resid,
    int M, int N, int K) {
  __shared__ __align__(16) __hip_bfloat16 As[128 * 32];
  __shared__ __align__(16) __hip_bfloat16 Bs[128 * 32];
  const int tid = threadIdx.x;
  const int lane = tid & 63;
  const int wid = tid >> 6;
  const int m0 = blockIdx.y * 128;
  const int n0 = blockIdx.x * 128;
  const int wr = wid >> 1, wc = wid & 1;  // wave tile 64x64
  f32x4 acc[4][4] = {};
  const int nk = K >> 5;
  const int lr = lane & 15, lk = lane >> 4;
  for (int kt = 0; kt < nk; ++kt) {
#pragma unroll
    for (int it = 0; it < 2; ++it) {
      const int c = wid * 2 + it;        // chunk 0..7 (1KB each)
      const int e = c * 512 + lane * 8;  // elem idx (only for global addr)
      const int row = e >> 5, col = e & 31;
      GLD_LDS16(A + (size_t)(m0 + row) * K + kt * 32 + col, As + c * 512);
      GLD_LDS16(BT + (size_t)(n0 + row) * K + kt * 32 + col, Bs + c * 512);
    }
    __syncthreads();
    bf16x8 af[4], bfr[4];
#pragma unroll
    for (int i = 0; i < 4; ++i)
      af[i] = *(const bf16x8*)(As + (wr * 64 + i * 16 + lr) * 32 + lk * 8);
#pragma unroll
    for (int j = 0; j < 4; ++j)
      bfr[j] = *(const bf16x8*)(Bs + (wc * 64 + j * 16 + lr) * 32 + lk * 8);
#pragma unroll
    for (int i = 0; i < 4; ++i)
#pragma unroll
      for (int j = 0; j < 4; ++j)
        acc[i][j] = __builtin_amdgcn_mfma_f32_16x16x32_bf16(af[i], bfr[j],
                                                            acc[i][j], 0, 0, 0);
    __syncthreads();
  }
#pragma unroll
  for (int i = 0; i < 4; ++i)
#pragma unroll
    for (int j = 0; j < 4; ++j)
#pragma unroll
      for (int r = 0; r < 4; ++r) {
        const int row = m0 + wr * 64 + i * 16 + lk * 4 + r;
        const int col = n0 + wc * 64 + j * 16 + lr;
        const float v = acc[i][j][r];
        if (RESID) {
          ((float*)Cout)[(size_t)row * N + col] =
              resid[(size_t)row * N + col] + v;
        } else {
          ((__hip_bfloat16*)Cout)[(size_t)row * N + col] = __float2bfloat16(v);
        }
      }
}

// ---------------- Flash attention, 32x32 MFMA, O^T orientation -------------
// grid (16 qtiles, 32 b*h). block 256 = 4 waves x 32 q-rows. KV tile 64.
// qk  layout: [4096][2048] bf16 (Q cols 0..1023, K cols 1024..2047)
// vT  layout: [1024][4096] bf16 (V^T: row = h*64+d, col = token)
// ctx layout: [4096][1024] bf16.
// LDS tiles 64x64 bf16, 128B rows, XOR swizzle byte^=(row&7)<<4 (T2).
__global__ __launch_bounds__(256, 2) void attn_kernel(
    const __hip_bfloat16* __restrict__ qk, const __hip_bfloat16* __restrict__ vT,
    __hip_bfloat16* __restrict__ ctx) {
  const int qt = blockIdx.x, bh = blockIdx.y;
  const int b = bh >> 4, h = bh & 15;
  const int tid = threadIdx.x, lane = tid & 63, wid = tid >> 6;
  const size_t tok0 = (size_t)b * 2048;
  const int q0 = qt * 128 + wid * 32;
  const int l31 = lane & 31;
  const int hi = lane >> 5;

  __shared__ __align__(16) char Kl[2][64 * 128];
  __shared__ __align__(16) char Vl[2][64 * 128];

  // staging: thread -> row sr (0..63), byte col chunk scB (0,32,64,96), 2x16B
  const int sr = tid >> 2;
  const int scB = (tid & 3) * 32;
  const int swW = (sr & 7) << 4;
  const int wA = sr * 128 + (scB ^ swW);
  const int wB = sr * 128 + ((scB + 16) ^ swW);

  const __hip_bfloat16* kbase = qk + tok0 * 2048 + 1024 + (size_t)h * 64;
  const __hip_bfloat16* vbase = vT + ((size_t)(h * 64 + sr)) * 4096 + tok0;
  const int scE = (tid & 3) * 16;  // element col base for global loads

  // Q B-operand frags: qf[ks] = Q[q0+l31][ks*16 + hi*8 .. +7], pre-scaled
  bf16x8 qf[4];
  {
    const __hip_bfloat16* qptr = qk + (tok0 + q0 + l31) * 2048 + h * 64 + hi * 8;
    const float c = 0.125f * 1.44269504f;
#pragma unroll
    for (int ks = 0; ks < 4; ++ks) {
      bf16x8 v = *(const bf16x8*)(qptr + ks * 16);
      const __hip_bfloat16* ie = (const __hip_bfloat16*)&v;
      __hip_bfloat16* oe = (__hip_bfloat16*)&qf[ks];
#pragma unroll
      for (int i = 0; i < 8; ++i)
        oe[i] = __float2bfloat16(__bfloat162float(ie[i]) * c);
    }
  }

  // per-lane swizzled read offsets
  const int swR = (l31 & 7) << 4;
  const int rb0 = l31 * 128;          // th/dh = 0 row base
  const int rb1 = (32 + l31) * 128;   // th/dh = 1

  bf16x8 kreg0, kreg1, vreg0, vreg1;
  auto load_tile = [&](int t) {
    const __hip_bfloat16* kp = kbase + (size_t)(t * 64 + sr) * 2048 + scE;
    kreg0 = *(const bf16x8*)kp;
    kreg1 = *(const bf16x8*)(kp + 8);
    const __hip_bfloat16* vp = vbase + t * 64 + scE;
    vreg0 = *(const bf16x8*)vp;
    vreg1 = *(const bf16x8*)(vp + 8);
  };
  auto write_tile = [&](int bf) {
    *(bf16x8*)(Kl[bf] + wA) = kreg0;
    *(bf16x8*)(Kl[bf] + wB) = kreg1;
    *(bf16x8*)(Vl[bf] + wA) = vreg0;
    *(bf16x8*)(Vl[bf] + wB) = vreg1;
  };

  f32x16 oT0 = {}, oT1 = {};  // O^T d-halves; lane col q=l31
  float mrow = -3e38f, lrow = 0.f;

  load_tile(0);
  write_tile(0);
  __syncthreads();

  for (int kvt = 0; kvt < 32; ++kvt) {
    const int cur = kvt & 1;
    if (kvt + 1 < 32) load_tile(kvt + 1);

    // S^T halves: s0 = tokens 0..31, s1 = 32..63 (D: col=q, row pattern)
    f32x16 s0 = {}, s1 = {};
#pragma unroll
    for (int ks = 0; ks < 4; ++ks) {
      const int cOff = (ks * 32 + hi * 16) ^ swR;
      const bf16x8 kf0 = *(const bf16x8*)(Kl[cur] + rb0 + cOff);
      const bf16x8 kf1 = *(const bf16x8*)(Kl[cur] + rb1 + cOff);
      s0 = __builtin_amdgcn_mfma_f32_32x32x16_bf16(kf0, qf[ks], s0, 0, 0, 0);
      s1 = __builtin_amdgcn_mfma_f32_32x32x16_bf16(kf1, qf[ks], s1, 0, 0, 0);
    }

    // online softmax (exp2 domain), q = l31 split across lane^32
    float mx = s0[0];
#pragma unroll
    for (int i = 1; i < 16; ++i) mx = fmaxf(mx, s0[i]);
#pragma unroll
    for (int i = 0; i < 16; ++i) mx = fmaxf(mx, s1[i]);
    mx = fmaxf(mx, __shfl_xor(mx, 32));
    const bool grow = (mx - mrow) > 8.0f;  // T13 defer-max
    if (__any(grow)) {
      const float mn = fmaxf(mrow, mx);
      const float alpha = exp2f(mrow - mn);
      mrow = mn;
      lrow *= alpha;
#pragma unroll
      for (int i = 0; i < 16; ++i) {
        oT0[i] *= alpha;
        oT1[i] *= alpha;
      }
    }
    float ps = 0.f;
    uint32_t pk0[8], pk1[8];
#pragma unroll
    for (int i = 0; i < 8; ++i) {
      const float a0 = exp2f(s0[2 * i] - mrow);
      const float a1 = exp2f(s0[2 * i + 1] - mrow);
      const float b0 = exp2f(s1[2 * i] - mrow);
      const float b1 = exp2f(s1[2 * i + 1] - mrow);
      ps += (a0 + a1) + (b0 + b1);
      pk0[i] = bfpack(a0, a1);
      pk1[i] = bfpack(b0, b1);
    }
    ps += __shfl_xor(ps, 32);
    lrow += ps;

    // PV: O^T += V^T * P^T, 4 token-steps x 2 d-halves
#pragma unroll
    for (int ts = 0; ts < 4; ++ts) {
      const uint32_t* pk = (ts < 2) ? pk0 : pk1;
      const int o = (ts & 1) * 4;
      const uint32_t L0 = pk[o], L1 = pk[o + 1];
      const uint32_t H0 = pk[o + 2], H1 = pk[o + 3];
      const uint32_t vS0 = hi ? L0 : H0, vS1 = hi ? L1 : H1;
      const uint32_t r0 = (uint32_t)__shfl_xor((int)vS0, 32);
      const uint32_t r1 = (uint32_t)__shfl_xor((int)vS1, 32);
      uint32_t fr[4] = {hi ? r0 : L0, hi ? r1 : L1, hi ? H0 : r0, hi ? H1 : r1};
      const bf16x8 pf = *(const bf16x8*)fr;
      const int cOff = (ts * 32 + hi * 16) ^ swR;
      const bf16x8 vf0 = *(const bf16x8*)(Vl[cur] + rb0 + cOff);
      const bf16x8 vf1 = *(const bf16x8*)(Vl[cur] + rb1 + cOff);
      oT0 = __builtin_amdgcn_mfma_f32_32x32x16_bf16(vf0, pf, oT0, 0, 0, 0);
      oT1 = __builtin_amdgcn_mfma_f32_32x32x16_bf16(vf1, pf, oT1, 0, 0, 0);
    }

    if (kvt + 1 < 32) write_tile(cur ^ 1);
    __syncthreads();
  }

  // epilogue: O^T lane holds q=l31, d = (r&3)+8*(r>>2)+4*hi+32*dh
  const float linv = 1.0f / lrow;
  __hip_bfloat16* cb = ctx + (tok0 + q0 + l31) * 1024 + h * 64;
#pragma unroll
  for (int dh = 0; dh < 2; ++dh) {
#pragma unroll
    for (int rq = 0; rq < 4; ++rq) {
      const int d0 = 8 * rq + 4 * hi + 32 * dh;
      float v0, v1, v2, v3;
      if (dh) {
        v0 = oT1[4 * rq];
        v1 = oT1[4 * rq + 1];
        v2 = oT1[4 * rq + 2];
        v3 = oT1[4 * rq + 3];
      } else {
        v0 = oT0[4 * rq];
        v1 = oT0[4 * rq + 1];
        v2 = oT0[4 * rq + 2];
        v3 = oT0[4 * rq + 3];
      }
      *(uint32_t*)(cb + d0) = bfpack(v0 * linv, v1 * linv);
      *(uint32_t*)(cb + d0 + 2) = bfpack(v2 * linv, v3 * linv);
    }
  }
}

extern "C" void kernel_launch(void* const* d_in, const int* in_sizes, int n_in,
                              void* d_out, int out_size, void* d_ws,
                              size_t ws_size, hipStream_t stream) {
  const float* x = (const float*)d_in[0];       // [2,2048,1024]
  const float* norm_w = (const float*)d_in[1];  // [1024]
  const float* w_qkv = (const float*)d_in[2];   // [1024,3072]
  const float* w_proj = (const float*)d_in[3];  // [1024,1024]
  float* out = (float*)d_out;                   // [2,2048,1024] f32

  char* ws = (char*)d_ws;
  __hip_bfloat16* hbuf = (__hip_bfloat16*)(ws);                               // 8 MB
  __hip_bfloat16* wqkvT = (__hip_bfloat16*)(ws + (size_t)8 * 1024 * 1024);    // 6 MB
  __hip_bfloat16* wprojT = (__hip_bfloat16*)(ws + (size_t)14 * 1024 * 1024);  // 2 MB
  __hip_bfloat16* qkbuf = (__hip_bfloat16*)(ws + (size_t)16 * 1024 * 1024);   // 16 MB
  __hip_bfloat16* vTbuf = (__hip_bfloat16*)(ws + (size_t)32 * 1024 * 1024);   // 8 MB
  __hip_bfloat16* ctx = (__hip_bfloat16*)(ws + (size_t)40 * 1024 * 1024);     // 8 MB

  rmsnorm_kernel<<<dim3(4096), dim3(256), 0, stream>>>(x, norm_w, hbuf);
  transpose_cast_kernel<<<dim3(96, 32), dim3(32, 8), 0, stream>>>(w_qkv, wqkvT,
                                                                  1024, 3072);
  transpose_cast_kernel<<<dim3(32, 32), dim3(32, 8), 0, stream>>>(
      w_proj, wprojT, 1024, 1024);
  // QK GEMM: [4096][2048] = h * (wqkvT rows 0..2047)^T
  gemm_bt_kernel<0><<<dim3(16, 32), dim3(256), 0, stream>>>(
      hbuf, wqkvT, (void*)qkbuf, nullptr, 4096, 2048, 1024);
  // V^T GEMM: [1024][4096] = (wqkvT rows 2048..3071) * h^T
  gemm_bt_kernel<0><<<dim3(32, 8), dim3(256), 0, stream>>>(
      wqkvT + (size_t)2048 * 1024, hbuf, (void*)vTbuf, nullptr, 1024, 4096,
      1024);
  attn_kernel<<<dim3(16, 32), dim3(256), 0, stream>>>(qkbuf, vTbuf, ctx);
  gemm_bt_kernel<1><<<dim3(8, 32), dim3(256), 0, stream>>>(
      ctx, wprojT, (void*)out, x, 4096, 1024, 1024);
}

// Round 5
// 145.652 us; speedup vs baseline: 1.5169x; 1.1488x over previous
//
#include <hip/hip_runtime.h>
#include <hip/hip_bf16.h>
#include <cstdint>
#include <cstddef>

typedef __attribute__((ext_vector_type(8))) short bf16x8;
typedef __attribute__((ext_vector_type(4))) float f32x4;
typedef __attribute__((ext_vector_type(16))) float f32x16;
typedef __attribute__((ext_vector_type(2))) float fv2;

#define GLD_LDS16(gptr, lptr)                                                  \
  __builtin_amdgcn_global_load_lds(                                            \
      (const __attribute__((address_space(1))) void*)(gptr),                   \
      (__attribute__((address_space(3))) void*)(lptr), 16, 0, 0)

__device__ __forceinline__ uint32_t cvtpk(float a, float b) {
  uint32_t d;
  asm("v_cvt_pk_bf16_f32 %0, %1, %2" : "=v"(d) : "v"(a), "v"(b));
  return d;
}

__device__ __forceinline__ fv2 pkadd(fv2 a, fv2 b) {
  fv2 d;
  asm("v_pk_add_f32 %0, %1, %2" : "=v"(d) : "v"(a), "v"(b));
  return d;
}

__device__ __forceinline__ float xhalf_max(float x) {
  auto r = __builtin_amdgcn_permlane32_swap(__float_as_uint(x),
                                            __float_as_uint(x), false, false);
  return fmaxf(__uint_as_float(r[0]), __uint_as_float(r[1]));
}

__device__ __forceinline__ float xhalf_sum(float x) {
  auto r = __builtin_amdgcn_permlane32_swap(__float_as_uint(x),
                                            __float_as_uint(x), false, false);
  return __uint_as_float(r[0]) + __uint_as_float(r[1]);
}

// ---------------- RMSNorm: x[4096][1024] f32 -> h bf16 ----------------
__global__ __launch_bounds__(256) void rmsnorm_kernel(
    const float* __restrict__ x, const float* __restrict__ w,
    __hip_bfloat16* __restrict__ h) {
  const int row = blockIdx.x;
  const int tid = threadIdx.x;
  const float4 v = reinterpret_cast<const float4*>(x + (size_t)row * 1024)[tid];
  float ss = v.x * v.x + v.y * v.y + v.z * v.z + v.w * v.w;
#pragma unroll
  for (int off = 32; off >= 1; off >>= 1) ss += __shfl_down(ss, off);
  __shared__ float red[4];
  if ((tid & 63) == 0) red[tid >> 6] = ss;
  __syncthreads();
  const float inv =
      rsqrtf((red[0] + red[1] + red[2] + red[3]) * (1.0f / 1024.0f) + 1e-6f);
  const float4 wv = reinterpret_cast<const float4*>(w)[tid];
  __hip_bfloat16* hp = h + (size_t)row * 1024 + tid * 4;
  hp[0] = __float2bfloat16(v.x * inv * wv.x);
  hp[1] = __float2bfloat16(v.y * inv * wv.y);
  hp[2] = __float2bfloat16(v.z * inv * wv.z);
  hp[3] = __float2bfloat16(v.w * inv * wv.w);
}

// ------- transpose+cast: src[R][C] f32 -> dst[C][R] bf16 --------
__global__ __launch_bounds__(256) void transpose_cast_kernel(
    const float* __restrict__ src, __hip_bfloat16* __restrict__ dst,
    int R, int C) {
  __shared__ float tile[32][33];
  const int bx = blockIdx.x * 32;  // C dim
  const int by = blockIdx.y * 32;  // R dim
  const int tx = threadIdx.x;      // 0..31
  const int ty = threadIdx.y;      // 0..7
#pragma unroll
  for (int j = 0; j < 32; j += 8)
    tile[ty + j][tx] = src[(size_t)(by + ty + j) * C + bx + tx];
  __syncthreads();
#pragma unroll
  for (int j = 0; j < 32; j += 8)
    dst[(size_t)(bx + ty + j) * R + by + tx] = __float2bfloat16(tile[tx][ty + j]);
}

// ---------------- GEMM: C[M][N] = A[M][K] * BT[N][K]^T ----------------
template <int RESID>
__global__ __launch_bounds__(256) void gemm_bt_kernel(
    const __hip_bfloat16* __restrict__ A, const __hip_bfloat16* __restrict__ BT,
    void* __restrict__ Cout, const float* __restrict__ resid,
    int M, int N, int K) {
  __shared__ __align__(16) __hip_bfloat16 As[128 * 32];
  __shared__ __align__(16) __hip_bfloat16 Bs[128 * 32];
  const int tid = threadIdx.x;
  const int lane = tid & 63;
  const int wid = tid >> 6;
  const int m0 = blockIdx.y * 128;
  const int n0 = blockIdx.x * 128;
  const int wr = wid >> 1, wc = wid & 1;  // wave tile 64x64
  f32x4 acc[4][4] = {};
  const int nk = K >> 5;
  const int lr = lane & 15, lk = lane >> 4;
  for (int kt = 0; kt < nk; ++kt) {
#pragma unroll
    for (int it = 0; it < 2; ++it) {
      const int c = wid * 2 + it;        // chunk 0..7 (1KB each)
      const int e = c * 512 + lane * 8;  // elem idx (only for global addr)
      const int row = e >> 5, col = e & 31;
      GLD_LDS16(A + (size_t)(m0 + row) * K + kt * 32 + col, As + c * 512);
      GLD_LDS16(BT + (size_t)(n0 + row) * K + kt * 32 + col, Bs + c * 512);
    }
    __syncthreads();
    bf16x8 af[4], bfr[4];
#pragma unroll
    for (int i = 0; i < 4; ++i)
      af[i] = *(const bf16x8*)(As + (wr * 64 + i * 16 + lr) * 32 + lk * 8);
#pragma unroll
    for (int j = 0; j < 4; ++j)
      bfr[j] = *(const bf16x8*)(Bs + (wc * 64 + j * 16 + lr) * 32 + lk * 8);
#pragma unroll
    for (int i = 0; i < 4; ++i)
#pragma unroll
      for (int j = 0; j < 4; ++j)
        acc[i][j] = __builtin_amdgcn_mfma_f32_16x16x32_bf16(af[i], bfr[j],
                                                            acc[i][j], 0, 0, 0);
    __syncthreads();
  }
#pragma unroll
  for (int i = 0; i < 4; ++i)
#pragma unroll
    for (int j = 0; j < 4; ++j)
#pragma unroll
      for (int r = 0; r < 4; ++r) {
        const int row = m0 + wr * 64 + i * 16 + lk * 4 + r;
        const int col = n0 + wc * 64 + j * 16 + lr;
        const float v = acc[i][j][r];
        if (RESID) {
          ((float*)Cout)[(size_t)row * N + col] =
              resid[(size_t)row * N + col] + v;
        } else {
          ((__hip_bfloat16*)Cout)[(size_t)row * N + col] = __float2bfloat16(v);
        }
      }
}

// ---------------- Flash attention, 32x32 MFMA, O^T orientation -------------
// grid (16 qtiles, 32 b*h). block 256 = 4 waves x 32 q-rows. KV tile 64.
// qk  layout: [4096][2048] bf16 (Q cols 0..1023, K cols 1024..2047)
// vT  layout: [1024][4096] bf16 (V^T: row = h*64+d, col = token)
// ctx layout: [4096][1024] bf16.
// LDS tiles 64x64 bf16, 128B rows, XOR swizzle byte^=(row&7)<<4 (T2).
__global__ __launch_bounds__(256, 2) void attn_kernel(
    const __hip_bfloat16* __restrict__ qk, const __hip_bfloat16* __restrict__ vT,
    __hip_bfloat16* __restrict__ ctx) {
  const int qt = blockIdx.x, bh = blockIdx.y;
  const int b = bh >> 4, h = bh & 15;
  const int tid = threadIdx.x, lane = tid & 63, wid = tid >> 6;
  const size_t tok0 = (size_t)b * 2048;
  const int q0 = qt * 128 + wid * 32;
  const int l31 = lane & 31;
  const int hi = lane >> 5;

  __shared__ __align__(16) char Kl[2][64 * 128];
  __shared__ __align__(16) char Vl[2][64 * 128];

  // staging: thread -> row sr (0..63), byte col chunk scB (0,32,64,96), 2x16B
  const int sr = tid >> 2;
  const int scB = (tid & 3) * 32;
  const int swW = (sr & 7) << 4;
  const int wA = sr * 128 + (scB ^ swW);
  const int wB = sr * 128 + ((scB + 16) ^ swW);

  const __hip_bfloat16* kbase = qk + tok0 * 2048 + 1024 + (size_t)h * 64;
  const __hip_bfloat16* vbase = vT + ((size_t)(h * 64 + sr)) * 4096 + tok0;
  const int scE = (tid & 3) * 16;  // element col base for global loads

  // Q B-operand frags: qf[ks] = Q[q0+l31][ks*16 + hi*8 .. +7], pre-scaled
  bf16x8 qf[4];
  {
    const __hip_bfloat16* qptr = qk + (tok0 + q0 + l31) * 2048 + h * 64 + hi * 8;
    const float c = 0.125f * 1.44269504f;
#pragma unroll
    for (int ks = 0; ks < 4; ++ks) {
      bf16x8 v = *(const bf16x8*)(qptr + ks * 16);
      const __hip_bfloat16* ie = (const __hip_bfloat16*)&v;
      __hip_bfloat16* oe = (__hip_bfloat16*)&qf[ks];
#pragma unroll
      for (int i = 0; i < 8; ++i)
        oe[i] = __float2bfloat16(__bfloat162float(ie[i]) * c);
    }
  }

  // per-lane swizzled read offsets
  const int swR = (l31 & 7) << 4;
  const int rb0 = l31 * 128;          // th/dh = 0 row base
  const int rb1 = (32 + l31) * 128;   // th/dh = 1

  bf16x8 kreg0, kreg1, vreg0, vreg1;
  auto load_tile = [&](int t) {
    const __hip_bfloat16* kp = kbase + (size_t)(t * 64 + sr) * 2048 + scE;
    kreg0 = *(const bf16x8*)kp;
    kreg1 = *(const bf16x8*)(kp + 8);
    const __hip_bfloat16* vp = vbase + t * 64 + scE;
    vreg0 = *(const bf16x8*)vp;
    vreg1 = *(const bf16x8*)(vp + 8);
  };
  auto write_tile = [&](int bf) {
    *(bf16x8*)(Kl[bf] + wA) = kreg0;
    *(bf16x8*)(Kl[bf] + wB) = kreg1;
    *(bf16x8*)(Vl[bf] + wA) = vreg0;
    *(bf16x8*)(Vl[bf] + wB) = vreg1;
  };

  f32x16 oT0 = {}, oT1 = {};  // O^T d-halves; lane col q=l31
  float mrow = -3e38f, lrow = 0.f;

  load_tile(0);
  write_tile(0);
  __syncthreads();

  for (int kvt = 0; kvt < 32; ++kvt) {
    const int cur = kvt & 1;
    if (kvt + 1 < 32) load_tile(kvt + 1);

    // S^T halves: s0 = tokens 0..31, s1 = 32..63 (D: col=q, row pattern)
    f32x16 s0 = {}, s1 = {};
#pragma unroll
    for (int ks = 0; ks < 4; ++ks) {
      const int cOff = (ks * 32 + hi * 16) ^ swR;
      const bf16x8 kf0 = *(const bf16x8*)(Kl[cur] + rb0 + cOff);
      const bf16x8 kf1 = *(const bf16x8*)(Kl[cur] + rb1 + cOff);
      s0 = __builtin_amdgcn_mfma_f32_32x32x16_bf16(kf0, qf[ks], s0, 0, 0, 0);
      s1 = __builtin_amdgcn_mfma_f32_32x32x16_bf16(kf1, qf[ks], s1, 0, 0, 0);
    }

    // max over the 32 S values (triples -> v_max3 fusion)
    const float m0_ = fmaxf(fmaxf(s0[0], s0[1]), s0[2]);
    const float m1_ = fmaxf(fmaxf(s0[3], s0[4]), s0[5]);
    const float m2_ = fmaxf(fmaxf(s0[6], s0[7]), s0[8]);
    const float m3_ = fmaxf(fmaxf(s0[9], s0[10]), s0[11]);
    const float m4_ = fmaxf(fmaxf(s0[12], s0[13]), s0[14]);
    const float m5_ = fmaxf(fmaxf(s0[15], s1[0]), s1[1]);
    const float m6_ = fmaxf(fmaxf(s1[2], s1[3]), s1[4]);
    const float m7_ = fmaxf(fmaxf(s1[5], s1[6]), s1[7]);
    const float m8_ = fmaxf(fmaxf(s1[8], s1[9]), s1[10]);
    const float m9_ = fmaxf(fmaxf(s1[11], s1[12]), s1[13]);
    const float ma_ = fmaxf(s1[14], s1[15]);
    const float n0_ = fmaxf(fmaxf(m0_, m1_), m2_);
    const float n1_ = fmaxf(fmaxf(m3_, m4_), m5_);
    const float n2_ = fmaxf(fmaxf(m6_, m7_), m8_);
    const float n3_ = fmaxf(m9_, ma_);
    float mx = fmaxf(fmaxf(fmaxf(n0_, n1_), n2_), n3_);
    mx = xhalf_max(mx);

    const bool grow = (mx - mrow) > 8.0f;  // T13 defer-max
    if (__any(grow)) {
      const float mn = fmaxf(mrow, mx);
      const float alpha = __builtin_amdgcn_exp2f(mrow - mn);
      mrow = mn;
      lrow *= alpha;
#pragma unroll
      for (int i = 0; i < 16; ++i) {
        oT0[i] *= alpha;
        oT1[i] *= alpha;
      }
    }

    // P = exp2(S - m) via packed bias + raw v_exp, pack to bf16 pairs
    const fv2 nm2 = {-mrow, -mrow};
    union {
      f32x16 v;
      fv2 p[8];
    } U0, U1;
    U0.v = s0;
    U1.v = s1;
#pragma unroll
    for (int i = 0; i < 8; ++i) {
      U0.p[i] = pkadd(U0.p[i], nm2);
      U1.p[i] = pkadd(U1.p[i], nm2);
    }
    float ps = 0.f;
    uint32_t pk0[8], pk1[8];
#pragma unroll
    for (int i = 0; i < 8; ++i) {
      const float a0 = __builtin_amdgcn_exp2f(U0.p[i].x);
      const float a1 = __builtin_amdgcn_exp2f(U0.p[i].y);
      const float b0 = __builtin_amdgcn_exp2f(U1.p[i].x);
      const float b1 = __builtin_amdgcn_exp2f(U1.p[i].y);
      ps += (a0 + a1) + (b0 + b1);
      pk0[i] = cvtpk(a0, a1);
      pk1[i] = cvtpk(b0, b1);
    }
    lrow += xhalf_sum(ps);

    // PV: O^T += V^T * P^T, 4 token-steps x 2 d-halves.
    // P^T frag via permlane32_swap: (w0,w2)=swap(L0,H0), (w1,w3)=swap(L1,H1)
#pragma unroll
    for (int ts = 0; ts < 4; ++ts) {
      const uint32_t* pk = (ts < 2) ? pk0 : pk1;
      const int o = (ts & 1) * 4;
      auto w02 = __builtin_amdgcn_permlane32_swap(pk[o], pk[o + 2], false, false);
      auto w13 =
          __builtin_amdgcn_permlane32_swap(pk[o + 1], pk[o + 3], false, false);
      uint32_t fr[4] = {w02[0], w13[0], w02[1], w13[1]};
      const bf16x8 pf = *(const bf16x8*)fr;
      const int cOff = (ts * 32 + hi * 16) ^ swR;
      const bf16x8 vf0 = *(const bf16x8*)(Vl[cur] + rb0 + cOff);
      const bf16x8 vf1 = *(const bf16x8*)(Vl[cur] + rb1 + cOff);
      oT0 = __builtin_amdgcn_mfma_f32_32x32x16_bf16(vf0, pf, oT0, 0, 0, 0);
      oT1 = __builtin_amdgcn_mfma_f32_32x32x16_bf16(vf1, pf, oT1, 0, 0, 0);
    }

    if (kvt + 1 < 32) write_tile(cur ^ 1);
    __syncthreads();
  }

  // epilogue: O^T lane holds q=l31, d = (r&3)+8*(r>>2)+4*hi+32*dh
  const float linv = 1.0f / lrow;
  __hip_bfloat16* cb = ctx + (tok0 + q0 + l31) * 1024 + h * 64;
#pragma unroll
  for (int dh = 0; dh < 2; ++dh) {
#pragma unroll
    for (int rq = 0; rq < 4; ++rq) {
      const int d0 = 8 * rq + 4 * hi + 32 * dh;
      float v0, v1, v2, v3;
      if (dh) {
        v0 = oT1[4 * rq];
        v1 = oT1[4 * rq + 1];
        v2 = oT1[4 * rq + 2];
        v3 = oT1[4 * rq + 3];
      } else {
        v0 = oT0[4 * rq];
        v1 = oT0[4 * rq + 1];
        v2 = oT0[4 * rq + 2];
        v3 = oT0[4 * rq + 3];
      }
      *(uint32_t*)(cb + d0) = cvtpk(v0 * linv, v1 * linv);
      *(uint32_t*)(cb + d0 + 2) = cvtpk(v2 * linv, v3 * linv);
    }
  }
}

extern "C" void kernel_launch(void* const* d_in, const int* in_sizes, int n_in,
                              void* d_out, int out_size, void* d_ws,
                              size_t ws_size, hipStream_t stream) {
  const float* x = (const float*)d_in[0];       // [2,2048,1024]
  const float* norm_w = (const float*)d_in[1];  // [1024]
  const float* w_qkv = (const float*)d_in[2];   // [1024,3072]
  const float* w_proj = (const float*)d_in[3];  // [1024,1024]
  float* out = (float*)d_out;                   // [2,2048,1024] f32

  char* ws = (char*)d_ws;
  __hip_bfloat16* hbuf = (__hip_bfloat16*)(ws);                               // 8 MB
  __hip_bfloat16* wqkvT = (__hip_bfloat16*)(ws + (size_t)8 * 1024 * 1024);    // 6 MB
  __hip_bfloat16* wprojT = (__hip_bfloat16*)(ws + (size_t)14 * 1024 * 1024);  // 2 MB
  __hip_bfloat16* qkbuf = (__hip_bfloat16*)(ws + (size_t)16 * 1024 * 1024);   // 16 MB
  __hip_bfloat16* vTbuf = (__hip_bfloat16*)(ws + (size_t)32 * 1024 * 1024);   // 8 MB
  __hip_bfloat16* ctx = (__hip_bfloat16*)(ws + (size_t)40 * 1024 * 1024);     // 8 MB

  rmsnorm_kernel<<<dim3(4096), dim3(256), 0, stream>>>(x, norm_w, hbuf);
  transpose_cast_kernel<<<dim3(96, 32), dim3(32, 8), 0, stream>>>(w_qkv, wqkvT,
                                                                  1024, 3072);
  transpose_cast_kernel<<<dim3(32, 32), dim3(32, 8), 0, stream>>>(
      w_proj, wprojT, 1024, 1024);
  // QK GEMM: [4096][2048] = h * (wqkvT rows 0..2047)^T
  gemm_bt_kernel<0><<<dim3(16, 32), dim3(256), 0, stream>>>(
      hbuf, wqkvT, (void*)qkbuf, nullptr, 4096, 2048, 1024);
  // V^T GEMM: [1024][4096] = (wqkvT rows 2048..3071) * h^T
  gemm_bt_kernel<0><<<dim3(32, 8), dim3(256), 0, stream>>>(
      wqkvT + (size_t)2048 * 1024, hbuf, (void*)vTbuf, nullptr, 1024, 4096,
      1024);
  attn_kernel<<<dim3(16, 32), dim3(256), 0, stream>>>(qkbuf, vTbuf, ctx);
  gemm_bt_kernel<1><<<dim3(8, 32), dim3(256), 0, stream>>>(
      ctx, wprojT, (void*)out, x, 4096, 1024, 1024);
}